// Round 5
// baseline (215.381 us; speedup 1.0000x reference)
//
#include <hip/hip_runtime.h>
#include <hip/hip_bf16.h>

typedef __hip_bfloat16 bf16;
typedef __attribute__((ext_vector_type(8))) short short8;   // 8 bf16 (4 VGPR)
typedef __attribute__((ext_vector_type(4))) float f32x4;    // MFMA acc

#define N_NODES 100000
#define N_EDGES 640000
#define NSB 98            // ceil(N_NODES / 1024)
#define N_TILES 6250      // N_NODES / 16
#define GE 313            // ceil(E/8/256) edge-processing blocks
#define HALF_BLKS 1024    // blocks per lin1 half-GEMM

// ---------------------------------------------------------------------------
__device__ __forceinline__ float bf2f(short s) {
    union { float f; unsigned u; } u;
    u.u = ((unsigned)(unsigned short)s) << 16;
    return u.f;
}
__device__ __forceinline__ short f2s(float f) {
    union { bf16 b; short s; } u;
    u.b = __float2bfloat16(f);
    return u.s;
}

// Per-wave dtype detection (wave-uniform, ~1 load/lane, L2-hot after block 0).
__device__ __forceinline__ int detect_is64(const int* __restrict__ idx) {
    int lane = threadIdx.x & 63;
    int v = idx[2 * (lane & 31) + 1];
    return __ballot(v == 0) == ~0ULL;
}
__device__ __forceinline__ int detect_f32(const unsigned* __restrict__ xw) {
    int lane = threadIdx.x & 63;
    unsigned e = (xw[lane] >> 7) & 0xFFu;
    int inr = (e >= 0x20u && e <= 0x4Fu);
    return __popcll(__ballot(inr)) < 48;   // few valid bf16 patterns => f32
}

// ---------------------------------------------------------------------------
// Edge decode: 8 edges per thread, int4 vector loads. E % 2048 == 0.
__device__ __forceinline__ void decode8(
        const int* __restrict__ eidx, int is64, int e0, int E,
        int (&ss)[8], int (&dd)[8]) {
    if (is64) {
        int4 a0 = *(const int4*)&eidx[2 * e0];
        int4 a1 = *(const int4*)&eidx[2 * e0 + 4];
        int4 a2 = *(const int4*)&eidx[2 * e0 + 8];
        int4 a3 = *(const int4*)&eidx[2 * e0 + 12];
        int4 b0 = *(const int4*)&eidx[2 * (E + e0)];
        int4 b1 = *(const int4*)&eidx[2 * (E + e0) + 4];
        int4 b2 = *(const int4*)&eidx[2 * (E + e0) + 8];
        int4 b3 = *(const int4*)&eidx[2 * (E + e0) + 12];
        ss[0] = a0.x; ss[1] = a0.z; ss[2] = a1.x; ss[3] = a1.z;
        ss[4] = a2.x; ss[5] = a2.z; ss[6] = a3.x; ss[7] = a3.z;
        dd[0] = b0.x; dd[1] = b0.z; dd[2] = b1.x; dd[3] = b1.z;
        dd[4] = b2.x; dd[5] = b2.z; dd[6] = b3.x; dd[7] = b3.z;
    } else {
        int4 s0 = *(const int4*)&eidx[e0];
        int4 s1 = *(const int4*)&eidx[e0 + 4];
        int4 d0 = *(const int4*)&eidx[E + e0];
        int4 d1 = *(const int4*)&eidx[E + e0 + 4];
        ss[0] = s0.x; ss[1] = s0.y; ss[2] = s0.z; ss[3] = s0.w;
        ss[4] = s1.x; ss[5] = s1.y; ss[6] = s1.z; ss[7] = s1.w;
        dd[0] = d0.x; dd[1] = d0.y; dd[2] = d0.z; dd[3] = d0.w;
        dd[4] = d1.x; dd[5] = d1.y; dd[6] = d1.z; dd[7] = d1.w;
    }
}

// ===========================================================================
// MFMA fragment helpers (16x16x32 bf16):
//   A[m][k]: m = lane&15, k = quad*8 + j   (16B contiguous per lane)
//   B[k][n]: n = lane&15, k = quad*8 + j   (same per-lane data layout!)
//   C/D:     col = lane&15, row = quad*4 + reg
// Operand-swap trick: compute D = W·X^T (W as A, x as B). Per-lane loads are
// IDENTICAL to X·W^T; D has col = node, row = dim -> each lane's 4 acc regs
// are 4 CONSECUTIVE output dims -> packed 8B stores.
// ===========================================================================
__device__ __forceinline__ short8 load_frag(const void* base, size_t eoff, int f32) {
    if (f32) {
        const float4* p = (const float4*)((const float*)base + eoff);
        const float4 u = p[0], v = p[1];
        short8 r;
        r[0] = f2s(u.x); r[1] = f2s(u.y); r[2] = f2s(u.z); r[3] = f2s(u.w);
        r[4] = f2s(v.x); r[5] = f2s(v.y); r[6] = f2s(v.z); r[7] = f2s(v.w);
        return r;
    }
    return *(const short8*)((const short*)base + eoff);
}

// ===========================================================================
// K1 three-way union:
//   blocks 0..GE-1:              hist (atomic deg++ + rank)
//   blocks GE..GE+1023:          xl = x @ W1l^T   (one weight bank, 16KB LDS)
//   blocks GE+1024..GE+2047:     xr = x @ W1r^T
// Round-4 lesson: the 2-bank union had 32KB LDS charged to ALL blocks
// (5 blk/CU cap) and a strangled 56-VGPR allocation (8 acc + 8 prefetch
// frags couldn't stay live) -> 54-61us, occ 21%. Halves need 4 acc + 4+4
// prefetch (clean regalloc) and 16KB LDS (10 blk/CU). x read twice; second
// pass is L3-hot (25.6MB << 256MB).
// ===========================================================================
__global__ __launch_bounds__(256) void k1_kernel(
        const void* __restrict__ x, const void* __restrict__ W1l,
        const void* __restrict__ W1r, bf16* __restrict__ xl,
        bf16* __restrict__ xr, const int* __restrict__ eidx,
        int* __restrict__ deg, int* __restrict__ rank) {
    __shared__ short wlds[16][64][8];   // 16 KB, one weight bank
    const int tid = threadIdx.x;
    const int bid = blockIdx.x;

    if (bid < GE) {
        // ---------------- hist part ----------------
        const int is64 = detect_is64(eidx);
        int e0 = (bid * 256 + tid) * 8;
        if (e0 >= N_EDGES) return;
        int ss[8], dd[8], rk[8];
        decode8(eidx, is64, e0, N_EDGES, ss, dd);
#pragma unroll
        for (int c = 0; c < 8; ++c) {
            bool ok = (unsigned)ss[c] < (unsigned)N_NODES &&
                      (unsigned)dd[c] < (unsigned)N_NODES;
            rk[c] = ok ? atomicAdd(&deg[dd[c]], 1) : 0;
        }
        *(int4*)&rank[e0]     = make_int4(rk[0], rk[1], rk[2], rk[3]);
        *(int4*)&rank[e0 + 4] = make_int4(rk[4], rk[5], rk[6], rk[7]);
        return;
    }

    // ---------------- lin1 half-GEMM ----------------
    const int half = (bid - GE) >> 10;         // 0 -> xl bank, 1 -> xr bank
    const int lb   = (bid - GE) & 1023;
    const void* W  = half ? W1r : W1l;
    bf16* outp     = half ? xr : xl;

    const int f32 = detect_f32((const unsigned*)x);
    {
        const int l = tid & 63, fg = tid >> 6;
        const int mm = l & 15, qq = l >> 4;
#pragma unroll
        for (int i = 0; i < 4; ++i) {
            const int f = fg * 4 + i;            // frag index = ks*4 + dt
            const int ks = f >> 2, dt = f & 3;
            const size_t wo = (size_t)(dt * 16 + mm) * 128 + ks * 32 + qq * 8;
            *(short8*)&wlds[f][l][0] = load_frag(W, wo, f32);
        }
    }
    __syncthreads();

    const int nwaves = HALF_BLKS * 4;
    const int wid = lb * 4 + (tid >> 6);
    const int lane = tid & 63;
    const int m = lane & 15, quad = lane >> 4;
    const short* w0 = &wlds[0][lane][0];

    int tile = wid;
    if (tile >= N_TILES) return;

    short8 a[4];
    {
        const size_t arow = (size_t)(tile * 16 + m) * 128 + quad * 8;
#pragma unroll
        for (int ks = 0; ks < 4; ++ks)
            a[ks] = load_frag(x, arow + ks * 32, f32);
    }

    while (true) {
        const int nxt = tile + nwaves;
        short8 an[4];
        if (nxt < N_TILES) {
            const size_t arow = (size_t)(nxt * 16 + m) * 128 + quad * 8;
#pragma unroll
            for (int ks = 0; ks < 4; ++ks)
                an[ks] = load_frag(x, arow + ks * 32, f32);
        }

        f32x4 acc[4];
#pragma unroll
        for (int dt = 0; dt < 4; ++dt) acc[dt] = (f32x4){0.f, 0.f, 0.f, 0.f};
#pragma unroll
        for (int ks = 0; ks < 4; ++ks)
#pragma unroll
            for (int dt = 0; dt < 4; ++dt) {
                const short8 w = *(const short8*)(w0 + (ks * 4 + dt) * 512);
                acc[dt] = __builtin_amdgcn_mfma_f32_16x16x32_bf16(
                    w, a[ks], acc[dt], 0, 0, 0);   // swapped operands
            }

        const int node = tile * 16 + m;
#pragma unroll
        for (int dt = 0; dt < 4; ++dt) {
            short4 p;
            p.x = f2s(acc[dt][0]); p.y = f2s(acc[dt][1]);
            p.z = f2s(acc[dt][2]); p.w = f2s(acc[dt][3]);
            *(short4*)((short*)outp + (size_t)node * 64 + dt * 16 + quad * 4) = p;
        }

        if (nxt >= N_TILES) break;
        tile = nxt;
#pragma unroll
        for (int ks = 0; ks < 4; ++ks) a[ks] = an[ks];
    }
}

// --- Coalesced 2-level exclusive scan (separate dispatches — proven fast) ---
__global__ __launch_bounds__(256) void scan_partial_kernel(
        const int* __restrict__ deg, int* __restrict__ off,
        int* __restrict__ bsum, int N) {
    __shared__ int ss[256];
    const int tid = threadIdx.x, blk = blockIdx.x;
    const int base = blk * 1024 + tid * 4;
    int v[4], s = 0;
    if (base + 3 < N) {
        int4 dv = *(const int4*)&deg[base];
        v[0] = dv.x; v[1] = dv.y; v[2] = dv.z; v[3] = dv.w;
    } else {
#pragma unroll
        for (int c = 0; c < 4; ++c) v[c] = (base + c < N) ? deg[base + c] : 0;
    }
#pragma unroll
    for (int c = 0; c < 4; ++c) s += v[c];
    ss[tid] = s; __syncthreads();
    for (int o = 1; o < 256; o <<= 1) {
        int t = (tid >= o) ? ss[tid - o] : 0;
        __syncthreads();
        ss[tid] += t;
        __syncthreads();
    }
    int run = ss[tid] - s;                      // exclusive
    if (tid == 255) bsum[blk] = ss[255];
#pragma unroll
    for (int c = 0; c < 4; ++c) {
        if (base + c < N) off[base + c] = run;
        run += v[c];
    }
}

// scan_add with the bsum prefix folded in.
__global__ __launch_bounds__(256) void scan_add_kernel(
        int* __restrict__ off, const int* __restrict__ bsum, int N) {
    __shared__ int ss[NSB];
    const int blk = blockIdx.x, tid = threadIdx.x;
    if (tid < NSB) ss[tid] = bsum[tid];
    __syncthreads();
    int add = 0;
    for (int i = 0; i < blk; ++i) add += ss[i];   // LDS broadcast, ~100 cyc
    const int base = blk * 1024 + tid * 4;
#pragma unroll
    for (int c = 0; c < 4; ++c) {
        int i = base + c;
        if (i < N) off[i] += add;
    }
    if (blk == NSB - 1 && tid == 0)
        off[N] = add + ss[NSB - 1];               // total valid edges
}

// fill: srcs[off[d] + rank[e]] = s — no atomics, independent scattered stores.
__global__ __launch_bounds__(256) void fill_kernel(
        const int* __restrict__ eidx, const int* __restrict__ off,
        const int* __restrict__ rank, int* __restrict__ srcs, int E, int N) {
    const int is64 = detect_is64(eidx);
    int e0 = (blockIdx.x * 256 + threadIdx.x) * 8;
    if (e0 >= E) return;
    int ss[8], dd[8];
    decode8(eidx, is64, e0, E, ss, dd);
    int4 r0 = *(const int4*)&rank[e0];
    int4 r1 = *(const int4*)&rank[e0 + 4];
    const int rk[8] = {r0.x, r0.y, r0.z, r0.w, r1.x, r1.y, r1.z, r1.w};
#pragma unroll
    for (int c = 0; c < 8; ++c) {
        if ((unsigned)ss[c] >= (unsigned)N || (unsigned)dd[c] >= (unsigned)N) continue;
        srcs[off[dd[c]] + rk[c]] = ss[c];
    }
}

// ===========================================================================
// K3: gather1 + fused lin2. Block = 16 nodes. Phase 1 computes the h-tile
// (16x64) into LDS (exact former gather1, relu fused); phase 2: 4 waves each
// do one 16x16 output tile of the dual GEMM (2 MFMA), W2 frags preloaded.
// Kills the h HBM round-trip (25.6 MB) and the lin2 dispatch.
// ===========================================================================
__global__ __launch_bounds__(256) void gather1_lin2_kernel(
        const int* __restrict__ srcs, const int* __restrict__ off,
        const bf16* __restrict__ xl, const bf16* __restrict__ xr,
        const void* __restrict__ b1, const void* __restrict__ W2l,
        const void* __restrict__ W2r, bf16* __restrict__ hl,
        bf16* __restrict__ hr, const unsigned* __restrict__ xdet) {
    const int f32 = detect_f32(xdet);
    const int tid = threadIdx.x;
    const int lane = tid & 63, wave = tid >> 6;
    const int m = lane & 15, quad = lane >> 4;

    // preload this wave's W2 frags (nt = wave) before the long gather phase
    const void* Wb = (wave < 2) ? W2l : W2r;
    short8 bfrag[2];
#pragma unroll
    for (int ks = 0; ks < 2; ++ks)
        bfrag[ks] = load_frag(
            Wb, (size_t)((wave & 1) * 16 + m) * 64 + ks * 32 + quad * 8, f32);

    __shared__ short htile[16][72];   // +8 shorts pad: break 128B row stride

    // ---- phase 1: gather + combine -> h row chunk (4 dims) ----
    const int node = blockIdx.x * 16 + (tid >> 4);   // N % 16 == 0
    const int j = tid & 15;
    const int gbase = lane & ~15;
    const int a = off[node], b = off[node + 1];
    float a0 = 0.f, a1 = 0.f, a2 = 0.f, a3 = 0.f;
    for (int base = a; base < b; base += 16) {
        const int cdeg = min(b - base, 16);
        int sv = (j < cdeg) ? srcs[base + j] : 0;
        for (int bb = 0; bb < cdeg; bb += 4) {
#pragma unroll
            for (int t = 0; t < 4; ++t) {
                const int idx = bb + t;
                const int s = __shfl(sv, gbase + (idx < cdeg ? idx : 0));
                if (idx < cdeg) {
                    short4 v = *(const short4*)((const short*)xl + (size_t)s * 64 + j * 4);
                    a0 += bf2f(v.x); a1 += bf2f(v.y);
                    a2 += bf2f(v.z); a3 += bf2f(v.w);
                }
            }
        }
    }
    float b0, b1v, b2v, b3;
    if (f32) {
        float4 bb4 = *(const float4*)((const float*)b1 + j * 4);
        b0 = bb4.x; b1v = bb4.y; b2v = bb4.z; b3 = bb4.w;
    } else {
        short4 bb4 = *(const short4*)((const short*)b1 + j * 4);
        b0 = bf2f(bb4.x); b1v = bf2f(bb4.y); b2v = bf2f(bb4.z); b3 = bf2f(bb4.w);
    }
    short4 xr4 = *(const short4*)((const short*)xr + (size_t)node * 64 + j * 4);
    const float inv = 1.0f / fmaxf((float)(b - a), 1.0f);
    short4 o;
    o.x = f2s(fmaxf(a0 * inv + b0  + bf2f(xr4.x), 0.0f));
    o.y = f2s(fmaxf(a1 * inv + b1v + bf2f(xr4.y), 0.0f));
    o.z = f2s(fmaxf(a2 * inv + b2v + bf2f(xr4.z), 0.0f));
    o.w = f2s(fmaxf(a3 * inv + b3  + bf2f(xr4.w), 0.0f));
    *(short4*)&htile[tid >> 4][j * 4] = o;
    __syncthreads();

    // ---- phase 2: dual GEMM on the 16-node tile (wave nt = wave) ----
    short8 afr[2];
#pragma unroll
    for (int ks = 0; ks < 2; ++ks)
        afr[ks] = *(const short8*)&htile[m][ks * 32 + quad * 8];
    f32x4 acc = (f32x4){0.f, 0.f, 0.f, 0.f};
#pragma unroll
    for (int ks = 0; ks < 2; ++ks)
        acc = __builtin_amdgcn_mfma_f32_16x16x32_bf16(
            bfrag[ks], afr[ks], acc, 0, 0, 0);   // swapped operands

    bf16* dst = (wave < 2) ? hl : hr;
    const int onode = blockIdx.x * 16 + m;
    short4 p;
    p.x = f2s(acc[0]); p.y = f2s(acc[1]);
    p.z = f2s(acc[2]); p.w = f2s(acc[3]);
    *(short4*)((short*)dst + (size_t)onode * 32 + (wave & 1) * 16 + quad * 4) = p;
}

// ===========================================================================
// K4: gather2 + fused final epilogue. 8-lane group per node, lane owns 4 dims.
// out = sum(hl[src])/deg + b2 + hr
// ===========================================================================
__global__ __launch_bounds__(256) void gather2_kernel(
        const int* __restrict__ srcs, const int* __restrict__ off,
        const bf16* __restrict__ hl, const bf16* __restrict__ hr,
        const void* __restrict__ b2, void* __restrict__ out,
        const unsigned* __restrict__ xdet, int N) {
    const int f32 = detect_f32(xdet);
    const int tid = threadIdx.x;
    const int node = blockIdx.x * 32 + (tid >> 3);   // N % 32 == 0
    const int j = tid & 7;                           // dims j*4 .. j*4+3
    const int gbase = (tid & 63) & ~7;
    const int a = off[node], b = off[node + 1];
    float a0 = 0.f, a1 = 0.f, a2 = 0.f, a3 = 0.f;
    for (int base = a; base < b; base += 8) {
        const int cdeg = min(b - base, 8);
        int sv = (j < cdeg) ? srcs[base + j] : 0;
        for (int bb = 0; bb < cdeg; bb += 4) {
#pragma unroll
            for (int t = 0; t < 4; ++t) {
                const int idx = bb + t;
                const int s = __shfl(sv, gbase + (idx < cdeg ? idx : 0));
                if (idx < cdeg) {
                    short4 v = *(const short4*)((const short*)hl + (size_t)s * 32 + j * 4);
                    a0 += bf2f(v.x); a1 += bf2f(v.y);
                    a2 += bf2f(v.z); a3 += bf2f(v.w);
                }
            }
        }
    }
    float b0, b1v, b2v, b3;
    if (f32) {
        float4 bb4 = *(const float4*)((const float*)b2 + j * 4);
        b0 = bb4.x; b1v = bb4.y; b2v = bb4.z; b3 = bb4.w;
    } else {
        short4 bb4 = *(const short4*)((const short*)b2 + j * 4);
        b0 = bf2f(bb4.x); b1v = bf2f(bb4.y); b2v = bf2f(bb4.z); b3 = bf2f(bb4.w);
    }
    short4 hr4 = *(const short4*)((const short*)hr + (size_t)node * 32 + j * 4);
    const float inv = 1.0f / fmaxf((float)(b - a), 1.0f);
    const float v0 = a0 * inv + b0  + bf2f(hr4.x);
    const float v1 = a1 * inv + b1v + bf2f(hr4.y);
    const float v2 = a2 * inv + b2v + bf2f(hr4.z);
    const float v3 = a3 * inv + b3  + bf2f(hr4.w);
    if (f32) {
        *(float4*)((float*)out + (size_t)node * 32 + j * 4) =
            make_float4(v0, v1, v2, v3);
    } else {
        short4 o;
        o.x = f2s(v0); o.y = f2s(v1); o.z = f2s(v2); o.w = f2s(v3);
        *(short4*)((short*)out + (size_t)node * 32 + j * 4) = o;
    }
}

// ---------------------------------------------------------------------------
extern "C" void kernel_launch(void* const* d_in, const int* in_sizes, int n_in,
                              void* d_out, int out_size, void* d_ws, size_t ws_size,
                              hipStream_t stream) {
    const void* x   = d_in[0];
    const int*  eix = (const int*)d_in[1];
    const void* W1l = d_in[2];
    const void* b1  = d_in[3];
    const void* W1r = d_in[4];
    const void* W2l = d_in[5];
    const void* b2  = d_in[6];
    const void* W2r = d_in[7];

    const int N = N_NODES;
    const int E = N_EDGES;

    // Workspace layout:
    //   xl    bf16[N*64]   @ 256
    //   xr    bf16[N*64]   @ 256 + N*128
    //   (h slot unused — lin2 fused into gather1)
    //   hl    bf16[N*32]   @ 256 + N*384
    //   hr    bf16[N*32]   @ 256 + N*448
    //   off   int[N+4]
    //   deg   int[N]
    //   rank  int[E]
    //   srcs  int[E]
    //   bsum  int[NSB]
    char* ws = (char*)d_ws;
    bf16*  xl    = (bf16*)(ws + 256);
    bf16*  xr    = (bf16*)(ws + 256 + (size_t)N * 128);
    bf16*  hl    = (bf16*)(ws + 256 + (size_t)N * 384);
    bf16*  hr    = (bf16*)(ws + 256 + (size_t)N * 448);
    int*   off   = (int*) (ws + 256 + (size_t)N * 512);
    int*   deg   = off + (N + 4);
    int*   rank  = deg + N;
    int*   srcs  = rank + E;
    int*   bsum  = srcs + E;

    hipMemsetAsync(deg, 0, (size_t)N * 4, stream);

    // K1: hist (blocks 0..312) ∥ xl-half ∥ xr-half
    k1_kernel<<<GE + 2 * HALF_BLKS, 256, 0, stream>>>(
        x, W1l, W1r, xl, xr, eix, deg, rank);

    // CSR scan + fill: separate dispatches (round-3 fused version regressed
    // 60 us — device-scope fences force cross-XCD L2 writeback/invalidate)
    scan_partial_kernel<<<NSB, 256, 0, stream>>>(deg, off, bsum, N);
    scan_add_kernel<<<NSB, 256, 0, stream>>>(off, bsum, N);
    fill_kernel<<<GE, 256, 0, stream>>>(eix, off, rank, srcs, E, N);

    // K3: h = relu(sum(xl[src])/deg + b1 + xr); hl/hr = h @ W2{l,r}^T
    gather1_lin2_kernel<<<N / 16, 256, 0, stream>>>(
        srcs, off, xl, xr, b1, W2l, W2r, hl, hr, (const unsigned*)x);

    // K4: out = sum(hl[src])/deg + b2 + hr
    gather2_kernel<<<N / 32, 256, 0, stream>>>(
        srcs, off, hl, hr, b2, d_out, (const unsigned*)x, N);
}

// Round 6
// 207.982 us; speedup vs baseline: 1.0356x; 1.0356x over previous
//
#include <hip/hip_runtime.h>
#include <hip/hip_bf16.h>

typedef __hip_bfloat16 bf16;
typedef __attribute__((ext_vector_type(8))) short short8;   // 8 bf16 (4 VGPR)
typedef __attribute__((ext_vector_type(4))) float f32x4;    // MFMA acc

#define N_NODES 100000
#define N_EDGES 640000
#define NSB 98            // ceil(N_NODES / 1024)
#define N_TILES 6250      // N_NODES / 16
#define GE 313            // ceil(E/8/256) fill blocks
#define HB 625            // E/4/256 hist blocks (4 edges/thread)
#define LIN1_BLKS 1024

// ---------------------------------------------------------------------------
__device__ __forceinline__ float bf2f(short s) {
    union { float f; unsigned u; } u;
    u.u = ((unsigned)(unsigned short)s) << 16;
    return u.f;
}
__device__ __forceinline__ short f2s(float f) {
    union { bf16 b; short s; } u;
    u.b = __float2bfloat16(f);
    return u.s;
}

// Per-wave dtype detection (wave-uniform, ~1 load/lane, L2-hot after block 0).
__device__ __forceinline__ int detect_is64(const int* __restrict__ idx) {
    int lane = threadIdx.x & 63;
    int v = idx[2 * (lane & 31) + 1];
    return __ballot(v == 0) == ~0ULL;
}
__device__ __forceinline__ int detect_f32(const unsigned* __restrict__ xw) {
    int lane = threadIdx.x & 63;
    unsigned e = (xw[lane] >> 7) & 0xFFu;
    int inr = (e >= 0x20u && e <= 0x4Fu);
    return __popcll(__ballot(inr)) < 48;   // few valid bf16 patterns => f32
}

// ---------------------------------------------------------------------------
// Edge decode, 8 edges (fill) and 4 edges (hist) per thread. E % 2048 == 0.
__device__ __forceinline__ void decode8(
        const int* __restrict__ eidx, int is64, int e0, int E,
        int (&ss)[8], int (&dd)[8]) {
    if (is64) {
        int4 a0 = *(const int4*)&eidx[2 * e0];
        int4 a1 = *(const int4*)&eidx[2 * e0 + 4];
        int4 a2 = *(const int4*)&eidx[2 * e0 + 8];
        int4 a3 = *(const int4*)&eidx[2 * e0 + 12];
        int4 b0 = *(const int4*)&eidx[2 * (E + e0)];
        int4 b1 = *(const int4*)&eidx[2 * (E + e0) + 4];
        int4 b2 = *(const int4*)&eidx[2 * (E + e0) + 8];
        int4 b3 = *(const int4*)&eidx[2 * (E + e0) + 12];
        ss[0] = a0.x; ss[1] = a0.z; ss[2] = a1.x; ss[3] = a1.z;
        ss[4] = a2.x; ss[5] = a2.z; ss[6] = a3.x; ss[7] = a3.z;
        dd[0] = b0.x; dd[1] = b0.z; dd[2] = b1.x; dd[3] = b1.z;
        dd[4] = b2.x; dd[5] = b2.z; dd[6] = b3.x; dd[7] = b3.z;
    } else {
        int4 s0 = *(const int4*)&eidx[e0];
        int4 s1 = *(const int4*)&eidx[e0 + 4];
        int4 d0 = *(const int4*)&eidx[E + e0];
        int4 d1 = *(const int4*)&eidx[E + e0 + 4];
        ss[0] = s0.x; ss[1] = s0.y; ss[2] = s0.z; ss[3] = s0.w;
        ss[4] = s1.x; ss[5] = s1.y; ss[6] = s1.z; ss[7] = s1.w;
        dd[0] = d0.x; dd[1] = d0.y; dd[2] = d0.z; dd[3] = d0.w;
        dd[4] = d1.x; dd[5] = d1.y; dd[6] = d1.z; dd[7] = d1.w;
    }
}

__device__ __forceinline__ void decode4(
        const int* __restrict__ eidx, int is64, int e0, int E,
        int (&ss)[4], int (&dd)[4]) {
    if (is64) {
        int4 a0 = *(const int4*)&eidx[2 * e0];
        int4 a1 = *(const int4*)&eidx[2 * e0 + 4];
        int4 b0 = *(const int4*)&eidx[2 * (E + e0)];
        int4 b1 = *(const int4*)&eidx[2 * (E + e0) + 4];
        ss[0] = a0.x; ss[1] = a0.z; ss[2] = a1.x; ss[3] = a1.z;
        dd[0] = b0.x; dd[1] = b0.z; dd[2] = b1.x; dd[3] = b1.z;
    } else {
        int4 s0 = *(const int4*)&eidx[e0];
        int4 d0 = *(const int4*)&eidx[E + e0];
        ss[0] = s0.x; ss[1] = s0.y; ss[2] = s0.z; ss[3] = s0.w;
        dd[0] = d0.x; dd[1] = d0.y; dd[2] = d0.z; dd[3] = d0.w;
    }
}

// ===========================================================================
// hist: deg[d]++ (returning atomic) + rank. DEDICATED dispatch (round-5
// lesson: union with lin1 = sum + contention, not max — the GEMM's VMEM
// queues and 47MB writes sit in front of the atomics). 4 edges/thread,
// 625 blocks -> ~20 waves/CU of outstanding atomics (latency-bound op).
// ===========================================================================
__global__ __launch_bounds__(256) void hist_kernel(
        const int* __restrict__ eidx, int* __restrict__ deg,
        int* __restrict__ rank) {
    const int is64 = detect_is64(eidx);
    const int e0 = (blockIdx.x * 256 + threadIdx.x) * 4;
    int ss[4], dd[4], rk[4];
    decode4(eidx, is64, e0, N_EDGES, ss, dd);
#pragma unroll
    for (int c = 0; c < 4; ++c) {
        bool ok = (unsigned)ss[c] < (unsigned)N_NODES &&
                  (unsigned)dd[c] < (unsigned)N_NODES;
        rk[c] = ok ? atomicAdd(&deg[dd[c]], 1) : 0;
    }
    *(int4*)&rank[e0] = make_int4(rk[0], rk[1], rk[2], rk[3]);
}

// ===========================================================================
// MFMA fragment helpers (16x16x32 bf16):
//   A[m][k]: m = lane&15, k = quad*8 + j   (16B contiguous per lane)
//   B[k][n]: n = lane&15, k = quad*8 + j   (same per-lane data layout!)
//   C/D:     col = lane&15, row = quad*4 + reg
// Operand-swap trick: compute D = W·X^T (W as A, x as B) -> lane's 4 acc
// regs are 4 CONSECUTIVE output dims -> packed 8B stores.
// ===========================================================================
__device__ __forceinline__ short8 load_frag(const void* base, size_t eoff, int f32) {
    if (f32) {
        const float4* p = (const float4*)((const float*)base + eoff);
        const float4 u = p[0], v = p[1];
        short8 r;
        r[0] = f2s(u.x); r[1] = f2s(u.y); r[2] = f2s(u.z); r[3] = f2s(u.w);
        r[4] = f2s(v.x); r[5] = f2s(v.y); r[6] = f2s(v.z); r[7] = f2s(v.w);
        return r;
    }
    return *(const short8*)((const short*)base + eoff);
}

// Merged layer-1 GEMM (DEDICATED dispatch): xl = x@W1l^T AND xr = x@W1r^T,
// one pass over x. Both banks LDS-stationary (32KB), A prefetch-pipelined.
__global__ __launch_bounds__(256) void lin1_kernel(
        const void* __restrict__ x, const void* __restrict__ W1l,
        const void* __restrict__ W1r, bf16* __restrict__ xl,
        bf16* __restrict__ xr) {
    const int f32 = detect_f32((const unsigned*)x);
    __shared__ short wlds[2][16][64][8];   // 32 KB

    const int tid = threadIdx.x;
    {
        const int l = tid & 63, fg = tid >> 6;
        const int mm = l & 15, qq = l >> 4;
#pragma unroll
        for (int i = 0; i < 4; ++i) {
            const int f = fg * 4 + i;            // frag index = ks*4 + dt
            const int ks = f >> 2, dt = f & 3;
            const size_t wo = (size_t)(dt * 16 + mm) * 128 + ks * 32 + qq * 8;
            *(short8*)&wlds[0][f][l][0] = load_frag(W1l, wo, f32);
            *(short8*)&wlds[1][f][l][0] = load_frag(W1r, wo, f32);
        }
    }
    __syncthreads();

    const int nwaves = LIN1_BLKS * 4;
    const int wid = blockIdx.x * 4 + (tid >> 6);
    const int lane = tid & 63;
    const int m = lane & 15, quad = lane >> 4;
    const short* wl0 = &wlds[0][0][lane][0];
    const short* wr0 = &wlds[1][0][lane][0];

    int tile = wid;
    if (tile >= N_TILES) return;

    short8 a[4];
    {
        const size_t arow = (size_t)(tile * 16 + m) * 128 + quad * 8;
#pragma unroll
        for (int ks = 0; ks < 4; ++ks)
            a[ks] = load_frag(x, arow + ks * 32, f32);
    }

    while (true) {
        const int nxt = tile + nwaves;
        short8 an[4];
        if (nxt < N_TILES) {
            const size_t arow = (size_t)(nxt * 16 + m) * 128 + quad * 8;
#pragma unroll
            for (int ks = 0; ks < 4; ++ks)
                an[ks] = load_frag(x, arow + ks * 32, f32);
        }

        f32x4 accl[4], accr[4];
#pragma unroll
        for (int dt = 0; dt < 4; ++dt) {
            accl[dt] = (f32x4){0.f, 0.f, 0.f, 0.f};
            accr[dt] = (f32x4){0.f, 0.f, 0.f, 0.f};
        }
#pragma unroll
        for (int ks = 0; ks < 4; ++ks)
#pragma unroll
            for (int dt = 0; dt < 4; ++dt) {
                const short8 wl = *(const short8*)(wl0 + (ks * 4 + dt) * 512);
                const short8 wr = *(const short8*)(wr0 + (ks * 4 + dt) * 512);
                accl[dt] = __builtin_amdgcn_mfma_f32_16x16x32_bf16(
                    wl, a[ks], accl[dt], 0, 0, 0);   // swapped operands
                accr[dt] = __builtin_amdgcn_mfma_f32_16x16x32_bf16(
                    wr, a[ks], accr[dt], 0, 0, 0);
            }

        const int node = tile * 16 + m;
#pragma unroll
        for (int dt = 0; dt < 4; ++dt) {
            short4 pl, pr;
            pl.x = f2s(accl[dt][0]); pl.y = f2s(accl[dt][1]);
            pl.z = f2s(accl[dt][2]); pl.w = f2s(accl[dt][3]);
            pr.x = f2s(accr[dt][0]); pr.y = f2s(accr[dt][1]);
            pr.z = f2s(accr[dt][2]); pr.w = f2s(accr[dt][3]);
            *(short4*)((short*)xl + (size_t)node * 64 + dt * 16 + quad * 4) = pl;
            *(short4*)((short*)xr + (size_t)node * 64 + dt * 16 + quad * 4) = pr;
        }

        if (nxt >= N_TILES) break;
        tile = nxt;
#pragma unroll
        for (int ks = 0; ks < 4; ++ks) a[ks] = an[ks];
    }
}

// --- Coalesced 2-level exclusive scan (separate dispatches — proven fast) ---
__global__ __launch_bounds__(256) void scan_partial_kernel(
        const int* __restrict__ deg, int* __restrict__ off,
        int* __restrict__ bsum, int N) {
    __shared__ int ss[256];
    const int tid = threadIdx.x, blk = blockIdx.x;
    const int base = blk * 1024 + tid * 4;
    int v[4], s = 0;
    if (base + 3 < N) {
        int4 dv = *(const int4*)&deg[base];
        v[0] = dv.x; v[1] = dv.y; v[2] = dv.z; v[3] = dv.w;
    } else {
#pragma unroll
        for (int c = 0; c < 4; ++c) v[c] = (base + c < N) ? deg[base + c] : 0;
    }
#pragma unroll
    for (int c = 0; c < 4; ++c) s += v[c];
    ss[tid] = s; __syncthreads();
    for (int o = 1; o < 256; o <<= 1) {
        int t = (tid >= o) ? ss[tid - o] : 0;
        __syncthreads();
        ss[tid] += t;
        __syncthreads();
    }
    int run = ss[tid] - s;                      // exclusive
    if (tid == 255) bsum[blk] = ss[255];
#pragma unroll
    for (int c = 0; c < 4; ++c) {
        if (base + c < N) off[base + c] = run;
        run += v[c];
    }
}

// scan_add with the bsum prefix folded in.
__global__ __launch_bounds__(256) void scan_add_kernel(
        int* __restrict__ off, const int* __restrict__ bsum, int N) {
    __shared__ int ss[NSB];
    const int blk = blockIdx.x, tid = threadIdx.x;
    if (tid < NSB) ss[tid] = bsum[tid];
    __syncthreads();
    int add = 0;
    for (int i = 0; i < blk; ++i) add += ss[i];   // LDS broadcast, ~100 cyc
    const int base = blk * 1024 + tid * 4;
#pragma unroll
    for (int c = 0; c < 4; ++c) {
        int i = base + c;
        if (i < N) off[i] += add;
    }
    if (blk == NSB - 1 && tid == 0)
        off[N] = add + ss[NSB - 1];               // total valid edges
}

// fill: srcs[off[d] + rank[e]] = s — no atomics, independent scattered stores.
__global__ __launch_bounds__(256) void fill_kernel(
        const int* __restrict__ eidx, const int* __restrict__ off,
        const int* __restrict__ rank, int* __restrict__ srcs, int E, int N) {
    const int is64 = detect_is64(eidx);
    int e0 = (blockIdx.x * 256 + threadIdx.x) * 8;
    if (e0 >= E) return;
    int ss[8], dd[8];
    decode8(eidx, is64, e0, E, ss, dd);
    int4 r0 = *(const int4*)&rank[e0];
    int4 r1 = *(const int4*)&rank[e0 + 4];
    const int rk[8] = {r0.x, r0.y, r0.z, r0.w, r1.x, r1.y, r1.z, r1.w};
#pragma unroll
    for (int c = 0; c < 8; ++c) {
        if ((unsigned)ss[c] >= (unsigned)N || (unsigned)dd[c] >= (unsigned)N) continue;
        srcs[off[dd[c]] + rk[c]] = ss[c];
    }
}

// ===========================================================================
// K3: gather1 + fused lin2. Block = 16 nodes, 16-lane group per node, lane
// owns 4 dims. Inner batch widened 4 -> 8: 8 independent 8B loads in flight
// per lane (MLP x2) — the gathers are L2/L3-latency-bound, not BW-bound.
// Phase 2: 4 waves each do one 16x16 tile of the dual GEMM from LDS htile.
// ===========================================================================
__global__ __launch_bounds__(256) void gather1_lin2_kernel(
        const int* __restrict__ srcs, const int* __restrict__ off,
        const bf16* __restrict__ xl, const bf16* __restrict__ xr,
        const void* __restrict__ b1, const void* __restrict__ W2l,
        const void* __restrict__ W2r, bf16* __restrict__ hl,
        bf16* __restrict__ hr, const unsigned* __restrict__ xdet) {
    const int f32 = detect_f32(xdet);
    const int tid = threadIdx.x;
    const int lane = tid & 63, wave = tid >> 6;
    const int m = lane & 15, quad = lane >> 4;

    // preload this wave's W2 frags (nt = wave) before the long gather phase
    const void* Wb = (wave < 2) ? W2l : W2r;
    short8 bfrag[2];
#pragma unroll
    for (int ks = 0; ks < 2; ++ks)
        bfrag[ks] = load_frag(
            Wb, (size_t)((wave & 1) * 16 + m) * 64 + ks * 32 + quad * 8, f32);

    __shared__ short htile[16][72];   // +8 shorts pad: break 128B row stride

    // ---- phase 1: gather + combine -> h row chunk (4 dims) ----
    const int node = blockIdx.x * 16 + (tid >> 4);   // N % 16 == 0
    const int j = tid & 15;
    const int gbase = lane & ~15;
    const int a = off[node], b = off[node + 1];
    float a0 = 0.f, a1 = 0.f, a2 = 0.f, a3 = 0.f;
    for (int base = a; base < b; base += 16) {
        const int cdeg = min(b - base, 16);
        int sv = (j < cdeg) ? srcs[base + j] : 0;
        for (int bb = 0; bb < cdeg; bb += 8) {
            short4 v[8];
#pragma unroll
            for (int t = 0; t < 8; ++t) {
                const int idx = bb + t;
                const int s = __shfl(sv, gbase + (idx < cdeg ? idx : 0));
                if (idx < cdeg)
                    v[t] = *(const short4*)((const short*)xl + (size_t)s * 64 + j * 4);
                else
                    v[t] = make_short4(0, 0, 0, 0);
            }
#pragma unroll
            for (int t = 0; t < 8; ++t) {
                a0 += bf2f(v[t].x); a1 += bf2f(v[t].y);
                a2 += bf2f(v[t].z); a3 += bf2f(v[t].w);
            }
        }
    }
    float b0, b1v, b2v, b3;
    if (f32) {
        float4 bb4 = *(const float4*)((const float*)b1 + j * 4);
        b0 = bb4.x; b1v = bb4.y; b2v = bb4.z; b3 = bb4.w;
    } else {
        short4 bb4 = *(const short4*)((const short*)b1 + j * 4);
        b0 = bf2f(bb4.x); b1v = bf2f(bb4.y); b2v = bf2f(bb4.z); b3 = bf2f(bb4.w);
    }
    short4 xr4 = *(const short4*)((const short*)xr + (size_t)node * 64 + j * 4);
    const float inv = 1.0f / fmaxf((float)(b - a), 1.0f);
    short4 o;
    o.x = f2s(fmaxf(a0 * inv + b0  + bf2f(xr4.x), 0.0f));
    o.y = f2s(fmaxf(a1 * inv + b1v + bf2f(xr4.y), 0.0f));
    o.z = f2s(fmaxf(a2 * inv + b2v + bf2f(xr4.z), 0.0f));
    o.w = f2s(fmaxf(a3 * inv + b3  + bf2f(xr4.w), 0.0f));
    *(short4*)&htile[tid >> 4][j * 4] = o;
    __syncthreads();

    // ---- phase 2: dual GEMM on the 16-node tile (wave nt = wave) ----
    short8 afr[2];
#pragma unroll
    for (int ks = 0; ks < 2; ++ks)
        afr[ks] = *(const short8*)&htile[m][ks * 32 + quad * 8];
    f32x4 acc = (f32x4){0.f, 0.f, 0.f, 0.f};
#pragma unroll
    for (int ks = 0; ks < 2; ++ks)
        acc = __builtin_amdgcn_mfma_f32_16x16x32_bf16(
            bfrag[ks], afr[ks], acc, 0, 0, 0);   // swapped operands

    bf16* dst = (wave < 2) ? hl : hr;
    const int onode = blockIdx.x * 16 + m;
    short4 p;
    p.x = f2s(acc[0]); p.y = f2s(acc[1]);
    p.z = f2s(acc[2]); p.w = f2s(acc[3]);
    *(short4*)((short*)dst + (size_t)onode * 32 + (wave & 1) * 16 + quad * 4) = p;
}

// ===========================================================================
// K4: gather2 + fused final epilogue. 8-lane group per node, lane owns 4
// dims. Whole degree-chunk (8 edges) loaded in one batch: 8 loads in flight.
// out = sum(hl[src])/deg + b2 + hr
// ===========================================================================
__global__ __launch_bounds__(256) void gather2_kernel(
        const int* __restrict__ srcs, const int* __restrict__ off,
        const bf16* __restrict__ hl, const bf16* __restrict__ hr,
        const void* __restrict__ b2, void* __restrict__ out,
        const unsigned* __restrict__ xdet, int N) {
    const int f32 = detect_f32(xdet);
    const int tid = threadIdx.x;
    const int node = blockIdx.x * 32 + (tid >> 3);   // N % 32 == 0
    const int j = tid & 7;                           // dims j*4 .. j*4+3
    const int gbase = (tid & 63) & ~7;
    const int a = off[node], b = off[node + 1];
    float a0 = 0.f, a1 = 0.f, a2 = 0.f, a3 = 0.f;
    for (int base = a; base < b; base += 8) {
        const int cdeg = min(b - base, 8);
        int sv = (j < cdeg) ? srcs[base + j] : 0;
        short4 v[8];
#pragma unroll
        for (int t = 0; t < 8; ++t) {
            const int s = __shfl(sv, gbase + (t < cdeg ? t : 0));
            if (t < cdeg)
                v[t] = *(const short4*)((const short*)hl + (size_t)s * 32 + j * 4);
            else
                v[t] = make_short4(0, 0, 0, 0);
        }
#pragma unroll
        for (int t = 0; t < 8; ++t) {
            a0 += bf2f(v[t].x); a1 += bf2f(v[t].y);
            a2 += bf2f(v[t].z); a3 += bf2f(v[t].w);
        }
    }
    float b0, b1v, b2v, b3;
    if (f32) {
        float4 bb4 = *(const float4*)((const float*)b2 + j * 4);
        b0 = bb4.x; b1v = bb4.y; b2v = bb4.z; b3 = bb4.w;
    } else {
        short4 bb4 = *(const short4*)((const short*)b2 + j * 4);
        b0 = bf2f(bb4.x); b1v = bf2f(bb4.y); b2v = bf2f(bb4.z); b3 = bf2f(bb4.w);
    }
    short4 hr4 = *(const short4*)((const short*)hr + (size_t)node * 32 + j * 4);
    const float inv = 1.0f / fmaxf((float)(b - a), 1.0f);
    const float v0 = a0 * inv + b0  + bf2f(hr4.x);
    const float v1 = a1 * inv + b1v + bf2f(hr4.y);
    const float v2 = a2 * inv + b2v + bf2f(hr4.z);
    const float v3 = a3 * inv + b3  + bf2f(hr4.w);
    if (f32) {
        *(float4*)((float*)out + (size_t)node * 32 + j * 4) =
            make_float4(v0, v1, v2, v3);
    } else {
        short4 o;
        o.x = f2s(v0); o.y = f2s(v1); o.z = f2s(v2); o.w = f2s(v3);
        *(short4*)((short*)out + (size_t)node * 32 + j * 4) = o;
    }
}

// ---------------------------------------------------------------------------
extern "C" void kernel_launch(void* const* d_in, const int* in_sizes, int n_in,
                              void* d_out, int out_size, void* d_ws, size_t ws_size,
                              hipStream_t stream) {
    const void* x   = d_in[0];
    const int*  eix = (const int*)d_in[1];
    const void* W1l = d_in[2];
    const void* b1  = d_in[3];
    const void* W1r = d_in[4];
    const void* W2l = d_in[5];
    const void* b2  = d_in[6];
    const void* W2r = d_in[7];

    const int N = N_NODES;
    const int E = N_EDGES;

    // Workspace layout:
    //   xl    bf16[N*64]   @ 256
    //   xr    bf16[N*64]   @ 256 + N*128
    //   (h slot unused — lin2 fused into gather1)
    //   hl    bf16[N*32]   @ 256 + N*384
    //   hr    bf16[N*32]   @ 256 + N*448
    //   off   int[N+4]
    //   deg   int[N]
    //   rank  int[E]
    //   srcs  int[E]
    //   bsum  int[NSB]
    char* ws = (char*)d_ws;
    bf16*  xl    = (bf16*)(ws + 256);
    bf16*  xr    = (bf16*)(ws + 256 + (size_t)N * 128);
    bf16*  hl    = (bf16*)(ws + 256 + (size_t)N * 384);
    bf16*  hr    = (bf16*)(ws + 256 + (size_t)N * 448);
    int*   off   = (int*) (ws + 256 + (size_t)N * 512);
    int*   deg   = off + (N + 4);
    int*   rank  = deg + N;
    int*   srcs  = rank + E;
    int*   bsum  = srcs + E;

    hipMemsetAsync(deg, 0, (size_t)N * 4, stream);

    // hist: dedicated dispatch, 4 edges/thread (round-5 lesson: the
    // lin1∥hist union measured sum+contention, not max — de-fused)
    hist_kernel<<<HB, 256, 0, stream>>>(eix, deg, rank);

    // CSR scan + fill (round-3 lesson: keep as separate dispatches)
    scan_partial_kernel<<<NSB, 256, 0, stream>>>(deg, off, bsum, N);
    scan_add_kernel<<<NSB, 256, 0, stream>>>(off, bsum, N);
    fill_kernel<<<GE, 256, 0, stream>>>(eix, off, rank, srcs, E, N);

    // lin1: xl = x@W1l^T AND xr = x@W1r^T, one pass over x
    lin1_kernel<<<LIN1_BLKS, 256, 0, stream>>>(x, W1l, W1r, xl, xr);

    // K3: h = relu(sum(xl[src])/deg + b1 + xr); hl/hr = h @ W2{l,r}^T
    gather1_lin2_kernel<<<N / 16, 256, 0, stream>>>(
        srcs, off, xl, xr, b1, W2l, W2r, hl, hr, (const unsigned*)x);

    // K4: out = sum(hl[src])/deg + b2 + hr
    gather2_kernel<<<N / 32, 256, 0, stream>>>(
        srcs, off, hl, hr, b2, d_out, (const unsigned*)x, N);
}